// Round 4
// baseline (829.970 us; speedup 1.0000x reference)
//
#include <hip/hip_runtime.h>
#include <stdint.h>

// GCN layer: out = relu( segment_sum(vals * emb[cols], rows) @ W )
// Reordered: out = relu( segment_sum(vals * P[cols], rows) ), P = emb @ W.
// Deterministic, global-atomic-free pipeline:
//   detect dtype -> count_k (per-block,bucket counts, coalesced) ->
//   mscan_k (1 block: bucket totals -> boffs, in-place counts->bases) ->
//   Wt bf16 -> P = emb@W (MFMA) -> place_k (LDS multisplit, copy-out via
//   precomputed bases; runs ~84B with RB=256) -> ms2_k (per-bucket 256-bin
//   counting sort -> exact CSR + per-node offs) -> agg_k (wave/node,
//   pair-gather: 32 lanes per P row, 8 pairs in flight, shfl combine).
// Round-3 lesson: bcursor global atomics (1.1M into 6KB) + 21B copy-out
// runs at RB=64 were the hidden 370us; RB=256 + count/scan/place fixes.

typedef unsigned short u16;
typedef __attribute__((ext_vector_type(8))) short short8v;  // 8 bf16
typedef __attribute__((ext_vector_type(4))) float f32x4;    // MFMA C/D

#define RBSH 8
#define RB 256           // rows per bucket
#define NBMAX 512        // supports N <= 131072
#define MS_T 4096        // edges per multisplit tile
#define MS_PT 16         // edges per thread (256 threads)

__device__ __forceinline__ float b2f(u16 u) {
  union { unsigned i; float f; } x; x.i = ((unsigned)u) << 16; return x.f;
}
__device__ __forceinline__ u16 f2b(float f) {
  union { unsigned i; float f; } x; x.f = f;
  unsigned r = x.i + 0x7fffu + ((x.i >> 16) & 1u);
  return (u16)(r >> 16);
}
__device__ __forceinline__ float blo(unsigned u) {
  union { unsigned i; float f; } x; x.i = u << 16; return x.f;
}
__device__ __forceinline__ float bhi(unsigned u) {
  union { unsigned i; float f; } x; x.i = u & 0xFFFF0000u; return x.f;
}

// ---- dtype detect: adj_vals ~ U[0,1). As f32 words, low16 uniform
// (>=0x3F80 ~75%). As packed bf16 pairs, low16 is bf16 in [0,1) -> <0x3F80.
__global__ void detect_k(const unsigned* __restrict__ valsw, int* __restrict__ flag) {
  __shared__ int cnt;
  if (threadIdx.x == 0) cnt = 0;
  __syncthreads();
  int c = 0;
  for (int i = threadIdx.x; i < 4096; i += 256) {
    unsigned w = valsw[i];
    if ((w & 0xFFFFu) >= 0x3F80u) c++;
  }
  atomicAdd(&cnt, c);
  __syncthreads();
  if (threadIdx.x == 0) *flag = (cnt < 1024) ? 1 : 0;
}

// ---------------- pass A: per-(block,bucket) counts (coalesced out) ----------------
__global__ __launch_bounds__(256) void count_k(const int* __restrict__ rows,
                                               int* __restrict__ cnt, int E, int NB) {
  __shared__ int h[NBMAX];
  int tid = threadIdx.x;
  for (int b = tid; b < NB; b += 256) h[b] = 0;
  __syncthreads();
  int base = blockIdx.x * MS_T;
#pragma unroll
  for (int i = 0; i < MS_PT; ++i) {
    int e = base + i * 256 + tid;
    if (e < E) atomicAdd(&h[rows[e] >> RBSH], 1);
  }
  __syncthreads();
  for (int b = tid; b < NB; b += 256) cnt[(size_t)blockIdx.x * NB + b] = h[b];
}

// ---------------- pass B: 1 block; totals -> boffs; cnt -> bases in place ----------------
__global__ __launch_bounds__(512) void mscan_k(int* __restrict__ cnt,
                                               int* __restrict__ boffs,
                                               int NB, int NBLK) {
  __shared__ int part[512];
  int tid = threadIdx.x;
  int tot = 0;
  if (tid < NB)
    for (int blk = 0; blk < NBLK; ++blk) tot += cnt[(size_t)blk * NB + tid];
  part[tid] = (tid < NB) ? tot : 0;
  __syncthreads();
  for (int o = 1; o < 512; o <<= 1) {
    int v = (tid >= o) ? part[tid - o] : 0;
    __syncthreads();
    part[tid] += v;
    __syncthreads();
  }
  if (tid < NB) {
    int run = part[tid] - tot;  // exclusive
    boffs[tid] = run;
    for (int blk = 0; blk < NBLK; ++blk) {
      size_t idx = (size_t)blk * NB + tid;
      int c = cnt[idx];
      cnt[idx] = run;  // becomes base
      run += c;
    }
  }
  if (tid == 511) boffs[NB] = part[511];
}

// ---------------- pass C: LDS multisplit place (no global atomics) ----------------
// Entry: x = col | ((row & 255) << 17)  (col < 2^17), y = f32 bits of val.
template <bool BF16>
__global__ __launch_bounds__(256) void place_k(const int* __restrict__ flag,
                                               const int* __restrict__ rows,
                                               const int* __restrict__ cols,
                                               const void* __restrict__ valsv,
                                               const int* __restrict__ base,
                                               int2* __restrict__ pack, int E, int NB) {
  if (*flag != (BF16 ? 1 : 0)) return;
  __shared__ int hist[NBMAX + 1];  // becomes exclusive prefix
  __shared__ int gbase[NBMAX];
  __shared__ int part[256];
  __shared__ int2 buf[MS_T];
  __shared__ u16 brow[MS_T];
  int tid = threadIdx.x;
  int tbase = blockIdx.x * MS_T;

  for (int b = tid; b <= NB; b += 256) hist[b] = 0;
  for (int b = tid; b < NB; b += 256) gbase[b] = base[(size_t)blockIdx.x * NB + b];
  __syncthreads();

  int bk[MS_PT], ofs[MS_PT], cl[MS_PT], vb[MS_PT];
#pragma unroll
  for (int i = 0; i < MS_PT; ++i) {
    int e = tbase + i * 256 + tid;
    if (e < E) {
      int r = rows[e];
      bk[i] = r >> RBSH;
      cl[i] = cols[e] | ((r & (RB - 1)) << 17);
      float v = BF16 ? b2f(((const u16*)valsv)[e]) : ((const float*)valsv)[e];
      vb[i] = __float_as_int(v);
      ofs[i] = atomicAdd(&hist[bk[i]], 1);
    } else {
      bk[i] = -1; ofs[i] = 0; cl[i] = 0; vb[i] = 0;
    }
  }
  __syncthreads();

  // exclusive prefix of hist[0..NB) in place; hist[NB] = total
  int K = (NB + 255) >> 8;
  int lo = tid * K, hi = lo + K;
  if (hi > NB) hi = NB;
  if (lo > NB) lo = NB;
  int s = 0;
  for (int b = lo; b < hi; ++b) s += hist[b];
  part[tid] = s;
  __syncthreads();
  for (int o = 1; o < 256; o <<= 1) {
    int v = (tid >= o) ? part[tid - o] : 0;
    __syncthreads();
    part[tid] += v;
    __syncthreads();
  }
  int run = part[tid] - s;
  for (int b = lo; b < hi; ++b) {
    int c = hist[b];
    hist[b] = run;
    run += c;
  }
  if (tid == 255) hist[NB] = part[255];
  __syncthreads();

  // scatter to LDS (sorted by bucket)
#pragma unroll
  for (int i = 0; i < MS_PT; ++i) {
    if (bk[i] >= 0) {
      int slot = hist[bk[i]] + ofs[i];
      buf[slot] = make_int2(cl[i], vb[i]);
      brow[slot] = (u16)bk[i];
    }
  }
  __syncthreads();

  // coalesced-run copy out via precomputed bases
  int tot = hist[NB];
  for (int i = tid; i < tot; i += 256) {
    int b = brow[i];
    pack[gbase[b] + (i - hist[b])] = buf[i];
  }
}

// ---------------- pass D: per-bucket 256-bin counting sort -> exact CSR ----------------
__global__ __launch_bounds__(256) void ms2_k(const int* __restrict__ boffs,
                                             const int2* __restrict__ pack,
                                             int2* __restrict__ pack2,
                                             int* __restrict__ offs, int N, int NB) {
  __shared__ int bins[RB];
  __shared__ int part[256];
  int b = blockIdx.x;
  int tid = threadIdx.x;
  int beg = boffs[b], end = boffs[b + 1];
  bins[tid] = 0;
  __syncthreads();
  for (int i = beg + tid; i < end; i += 256)
    atomicAdd(&bins[(pack[i].x >> 17) & (RB - 1)], 1);
  __syncthreads();
  int c = bins[tid];
  part[tid] = c;
  __syncthreads();
  for (int o = 1; o < 256; o <<= 1) {
    int v = (tid >= o) ? part[tid - o] : 0;
    __syncthreads();
    part[tid] += v;
    __syncthreads();
  }
  int pfx = part[tid] - c;  // exclusive
  __syncthreads();
  int n = b * RB + tid;
  if (n < N) offs[n] = beg + pfx;
  if (b == NB - 1 && tid == 0) offs[N] = end;
  bins[tid] = pfx;  // cursors
  __syncthreads();
  for (int i = beg + tid; i < end; i += 256) {
    int2 q = pack[i];
    int r = (q.x >> 17) & (RB - 1);
    int p = atomicAdd(&bins[r], 1);
    pack2[beg + p] = q;
  }
}

// ---------------- W -> bf16, transposed: Wt[n][k] = W[k][n] ----------------
template <bool BF16>
__global__ void wtr_k(const int* __restrict__ flag, const void* __restrict__ Wv,
                      u16* __restrict__ Wt) {
  if (*flag != (BF16 ? 1 : 0)) return;
  int i = blockIdx.x * 256 + threadIdx.x;  // 65536 total
  int n = i >> 8, k = i & 255;
  float w = BF16 ? b2f(((const u16*)Wv)[k * 256 + n]) : ((const float*)Wv)[k * 256 + n];
  Wt[n * 256 + k] = f2b(w);
}

// ---------------- P = emb @ W via MFMA bf16 (verified) ----------------
template <bool BF16>
__global__ __launch_bounds__(256) void proj_k(const int* __restrict__ flag,
                                              const void* __restrict__ embv,
                                              const u16* __restrict__ Wt,
                                              u16* __restrict__ P, int N) {
  if (*flag != (BF16 ? 1 : 0)) return;
  int wave = threadIdx.x >> 6, lane = threadIdx.x & 63;
  int lr = lane & 15, lq = lane >> 4;
  int m0 = blockIdx.x * 64;
  int n0 = wave * 64;

  f32x4 acc[4][4];
#pragma unroll
  for (int mi = 0; mi < 4; ++mi)
#pragma unroll
    for (int ni = 0; ni < 4; ++ni) acc[mi][ni] = (f32x4)0.f;

  int arow[4];
#pragma unroll
  for (int mi = 0; mi < 4; ++mi) {
    int r = m0 + mi * 16 + lr;
    arow[mi] = r < N ? r : N - 1;
  }

  for (int ks = 0; ks < 8; ++ks) {
    int kb = ks * 32 + lq * 8;
    short8v a[4], b[4];
#pragma unroll
    for (int mi = 0; mi < 4; ++mi) {
      if (BF16) {
        a[mi] = *(const short8v*)((const u16*)embv + (size_t)arow[mi] * 256 + kb);
      } else {
        const float* p = (const float*)embv + (size_t)arow[mi] * 256 + kb;
        float4 x = *(const float4*)p;
        float4 y = *(const float4*)(p + 4);
        short8v t;
        t[0] = (short)f2b(x.x); t[1] = (short)f2b(x.y);
        t[2] = (short)f2b(x.z); t[3] = (short)f2b(x.w);
        t[4] = (short)f2b(y.x); t[5] = (short)f2b(y.y);
        t[6] = (short)f2b(y.z); t[7] = (short)f2b(y.w);
        a[mi] = t;
      }
    }
#pragma unroll
    for (int ni = 0; ni < 4; ++ni)
      b[ni] = *(const short8v*)(Wt + (size_t)(n0 + ni * 16 + lr) * 256 + kb);
#pragma unroll
    for (int mi = 0; mi < 4; ++mi)
#pragma unroll
      for (int ni = 0; ni < 4; ++ni)
        acc[mi][ni] = __builtin_amdgcn_mfma_f32_16x16x32_bf16(a[mi], b[ni], acc[mi][ni], 0, 0, 0);
  }

#pragma unroll
  for (int mi = 0; mi < 4; ++mi) {
    int rbase = m0 + mi * 16 + lq * 4;
#pragma unroll
    for (int ni = 0; ni < 4; ++ni) {
      int col = n0 + ni * 16 + lr;
#pragma unroll
      for (int r = 0; r < 4; ++r) {
        int row = rbase + r;
        if (row < N) P[(size_t)row * 256 + col] = f2b(acc[mi][ni][r]);
      }
    }
  }
}

// ---------------- aggregation: wave/node, pair-gather ----------------
// out[n][d] = relu( sum_e val_e * P[col_e][d] ).  Lanes 0-31 fetch edge j's
// P row (16B/lane), lanes 32-63 edge j+1's: 1KB per load instruction, 8
// pairs (16 edges) in flight. Halves combined once per node via shfl.
template <bool OUTBF16>
__global__ __launch_bounds__(256) void agg_k(const int* __restrict__ flag,
                                             const u16* __restrict__ P,
                                             const int* __restrict__ offs,
                                             const int2* __restrict__ pack,
                                             void* __restrict__ outv, int N) {
  if (*flag != (OUTBF16 ? 1 : 0)) return;
  int wave = threadIdx.x >> 6, lane = threadIdx.x & 63;
  int node = blockIdx.x * 4 + wave;
  if (node >= N) return;
  int sub = lane & 31, half = lane >> 5;
  int beg = offs[node], end = offs[node + 1];
  const u16* pb = P + sub * 8;

  float acc[8];
#pragma unroll
  for (int k = 0; k < 8; ++k) acc[k] = 0.f;

  for (int j = beg; j < end; j += 16) {
#pragma unroll
    for (int k = 0; k < 8; ++k) {
      int i0 = j + 2 * k + half;           // my edge (uniform per half)
      int ic = i0 < end ? i0 : end - 1;    // clamped load index
      int2 q = pack[ic];
      float v = i0 < end ? __int_as_float(q.y) : 0.f;
      const int4* src = (const int4*)(pb + (size_t)(q.x & 0x1FFFF) * 256);
      int4 u = *src;
      acc[0] += v * blo((unsigned)u.x); acc[1] += v * bhi((unsigned)u.x);
      acc[2] += v * blo((unsigned)u.y); acc[3] += v * bhi((unsigned)u.y);
      acc[4] += v * blo((unsigned)u.z); acc[5] += v * bhi((unsigned)u.z);
      acc[6] += v * blo((unsigned)u.w); acc[7] += v * bhi((unsigned)u.w);
    }
  }

  // combine halves: lane l += lane l^32 (same dims, other edge parity)
#pragma unroll
  for (int k = 0; k < 8; ++k) acc[k] += __shfl(acc[k], lane ^ 32);

  // each half stores 4 of the 8 dims: dim = sub*8 + half*4 + k
#pragma unroll
  for (int k = 0; k < 8; ++k) acc[k] = fmaxf(acc[k], 0.f);
  int d0 = sub * 8 + half * 4;
  if (OUTBF16) {
    ushort4 o;
    o.x = f2b(acc[half * 4 + 0]); o.y = f2b(acc[half * 4 + 1]);
    o.z = f2b(acc[half * 4 + 2]); o.w = f2b(acc[half * 4 + 3]);
    *(ushort4*)((u16*)outv + (size_t)node * 256 + d0) = o;
  } else {
    float4 o;
    o.x = acc[half * 4 + 0]; o.y = acc[half * 4 + 1];
    o.z = acc[half * 4 + 2]; o.w = acc[half * 4 + 3];
    *(float4*)((float*)outv + (size_t)node * 256 + d0) = o;
  }
}

// ---------------- launch ----------------

extern "C" void kernel_launch(void* const* d_in, const int* in_sizes, int n_in,
                              void* d_out, int out_size, void* d_ws, size_t ws_size,
                              hipStream_t stream) {
  const void* emb  = d_in[0];
  const int*  rows = (const int*)d_in[1];
  const int*  cols = (const int*)d_in[2];
  const void* vals = d_in[3];
  const void* W    = d_in[4];

  int N = in_sizes[0] / 256;
  int E = in_sizes[1];
  int NB = (N + RB - 1) >> RBSH;
  int NBLK = (E + MS_T - 1) / MS_T;

  char* ws = (char*)d_ws;
  size_t off = 0;
  auto carve = [&](size_t bytes) -> char* {
    char* p = ws + off;
    off += (bytes + 511) & ~(size_t)511;
    return p;
  };
  int*  flag  = (int*) carve(4);
  int*  cnt   = (int*) carve((size_t)NBLK * NB * 4);  // counts -> bases
  int*  boffs = (int*) carve((size_t)(NB + 1) * 4);
  int*  offs  = (int*) carve((size_t)(N + 1) * 4);
  int2* pack  = (int2*)carve((size_t)E * 8);
  int2* pack2 = (int2*)carve((size_t)E * 8);
  u16*  P     = (u16*) carve((size_t)N * 256 * 2);
  u16*  Wt    = (u16*) carve((size_t)256 * 256 * 2);
  (void)ws_size; (void)n_in; (void)out_size;

  detect_k<<<1, 256, 0, stream>>>((const unsigned*)vals, flag);

  count_k<<<NBLK, 256, 0, stream>>>(rows, cnt, E, NB);
  mscan_k<<<1, 512, 0, stream>>>(cnt, boffs, NB, NBLK);

  wtr_k<true ><<<256, 256, 0, stream>>>(flag, W, Wt);
  wtr_k<false><<<256, 256, 0, stream>>>(flag, W, Wt);

  int pb = (N + 63) / 64;
  proj_k<true ><<<pb, 256, 0, stream>>>(flag, emb, Wt, P, N);
  proj_k<false><<<pb, 256, 0, stream>>>(flag, emb, Wt, P, N);

  place_k<true ><<<NBLK, 256, 0, stream>>>(flag, rows, cols, vals, cnt, pack, E, NB);
  place_k<false><<<NBLK, 256, 0, stream>>>(flag, rows, cols, vals, cnt, pack, E, NB);

  ms2_k<<<NB, 256, 0, stream>>>(boffs, pack, pack2, offs, N, NB);

  int ab = (N + 3) / 4;
  agg_k<true ><<<ab, 256, 0, stream>>>(flag, P, offs, pack2, d_out, N);
  agg_k<false><<<ab, 256, 0, stream>>>(flag, P, offs, pack2, d_out, N);
}

// Round 5
// 586.275 us; speedup vs baseline: 1.4157x; 1.4157x over previous
//
#include <hip/hip_runtime.h>
#include <stdint.h>

// GCN layer: out = relu( segment_sum(vals * emb[cols], rows) @ W )
// Reordered: out = relu( segment_sum(vals * P[cols], rows) ), P = emb @ W.
// Deterministic, global-atomic-free pipeline (9 launches):
//   detect -> count_k (per-block,bucket counts) -> rowscan_k (391 blocks,
//   within-bucket prefix over count-blocks, parallel) -> boffscan_k (1 block,
//   bucket bases) -> wtr (W^T bf16) -> proj (P=emb@W MFMA) -> place_k
//   (LDS multisplit, copy-out via precomputed bases) -> ms2_k (per-bucket
//   256-bin counting sort -> exact CSR) -> agg_k (wave/node pair-gather).
// Round-4 lesson: one-block serial scan over 782 strided lines x2 = 266us
// of pure latency; scan must be parallel-per-bucket. Dual-flavor dead
// launches replaced by wave-uniform runtime dtype branches (14 -> 9).

typedef unsigned short u16;
typedef __attribute__((ext_vector_type(8))) short short8v;  // 8 bf16
typedef __attribute__((ext_vector_type(4))) float f32x4;    // MFMA C/D

#define RBSH 8
#define RB 256           // rows per bucket
#define NBMAX 512        // supports N <= 131072
#define MS_T 4096        // edges per multisplit tile
#define MS_PT 16         // edges per thread (256 threads)

__device__ __forceinline__ float b2f(u16 u) {
  union { unsigned i; float f; } x; x.i = ((unsigned)u) << 16; return x.f;
}
__device__ __forceinline__ u16 f2b(float f) {
  union { unsigned i; float f; } x; x.f = f;
  unsigned r = x.i + 0x7fffu + ((x.i >> 16) & 1u);
  return (u16)(r >> 16);
}
__device__ __forceinline__ float blo(unsigned u) {
  union { unsigned i; float f; } x; x.i = u << 16; return x.f;
}
__device__ __forceinline__ float bhi(unsigned u) {
  union { unsigned i; float f; } x; x.i = u & 0xFFFF0000u; return x.f;
}

// ---- dtype detect: adj_vals ~ U[0,1). As f32 words, low16 uniform
// (>=0x3F80 ~75%). As packed bf16 pairs, low16 is bf16 in [0,1) -> <0x3F80.
__global__ void detect_k(const unsigned* __restrict__ valsw, int* __restrict__ flag) {
  __shared__ int cnt;
  if (threadIdx.x == 0) cnt = 0;
  __syncthreads();
  int c = 0;
  for (int i = threadIdx.x; i < 4096; i += 256) {
    unsigned w = valsw[i];
    if ((w & 0xFFFFu) >= 0x3F80u) c++;
  }
  atomicAdd(&cnt, c);
  __syncthreads();
  if (threadIdx.x == 0) *flag = (cnt < 1024) ? 1 : 0;
}

// ---------------- pass A: per-(block,bucket) counts (coalesced out) ----------------
__global__ __launch_bounds__(256) void count_k(const int* __restrict__ rows,
                                               int* __restrict__ cnt, int E, int NB) {
  __shared__ int h[NBMAX];
  int tid = threadIdx.x;
  for (int b = tid; b < NB; b += 256) h[b] = 0;
  __syncthreads();
  int base = blockIdx.x * MS_T;
#pragma unroll
  for (int i = 0; i < MS_PT; ++i) {
    int e = base + i * 256 + tid;
    if (e < E) atomicAdd(&h[rows[e] >> RBSH], 1);
  }
  __syncthreads();
  for (int b = tid; b < NB; b += 256) cnt[(size_t)blockIdx.x * NB + b] = h[b];
}

// ---------------- pass B1: within-bucket prefix over count-blocks ----------------
// One block per bucket. cnt[blk*NB + b] -> exclusive prefix (in place);
// totals[b] = bucket total. 256 threads x up to 8 contiguous blk each.
__global__ __launch_bounds__(256) void rowscan_k(int* __restrict__ cnt,
                                                 int* __restrict__ totals,
                                                 int NB, int NBLK) {
  __shared__ int part[256];
  int b = blockIdx.x, tid = threadIdx.x;
  int K = (NBLK + 255) >> 8;  // <= 8 for NBLK <= 2048
  int lo = tid * K;
  int v[8];
  int s = 0;
#pragma unroll
  for (int u = 0; u < 8; ++u) {
    int i = lo + u;
    v[u] = (u < K && i < NBLK) ? cnt[(size_t)i * NB + b] : 0;
    s += v[u];
  }
  part[tid] = s;
  __syncthreads();
  for (int o = 1; o < 256; o <<= 1) {
    int t = (tid >= o) ? part[tid - o] : 0;
    __syncthreads();
    part[tid] += t;
    __syncthreads();
  }
  int run = part[tid] - s;  // exclusive base for this thread's range
#pragma unroll
  for (int u = 0; u < 8; ++u) {
    int i = lo + u;
    if (u < K && i < NBLK) cnt[(size_t)i * NB + b] = run;
    run += v[u];
  }
  if (tid == 255) totals[b] = part[255];
}

// ---------------- pass B2: bucket bases (1 block, NB <= 512) ----------------
__global__ __launch_bounds__(512) void boffscan_k(const int* __restrict__ totals,
                                                  int* __restrict__ boffs, int NB) {
  __shared__ int part[512];
  int tid = threadIdx.x;
  int c = (tid < NB) ? totals[tid] : 0;
  part[tid] = c;
  __syncthreads();
  for (int o = 1; o < 512; o <<= 1) {
    int t = (tid >= o) ? part[tid - o] : 0;
    __syncthreads();
    part[tid] += t;
    __syncthreads();
  }
  if (tid < NB) boffs[tid] = part[tid] - c;
  if (tid == 511) boffs[NB] = part[511];
}

// ---------------- pass C: LDS multisplit place (no global atomics) ----------------
// Entry: x = col | ((row & 255) << 17)  (col < 2^17), y = f32 bits of val.
__global__ __launch_bounds__(256) void place_k(const int* __restrict__ flag,
                                               const int* __restrict__ rows,
                                               const int* __restrict__ cols,
                                               const void* __restrict__ valsv,
                                               const int* __restrict__ base,
                                               const int* __restrict__ boffs,
                                               int2* __restrict__ pack, int E, int NB) {
  __shared__ int hist[NBMAX + 1];  // becomes exclusive prefix
  __shared__ int gbase[NBMAX];
  __shared__ int part[256];
  __shared__ int2 buf[MS_T];
  __shared__ u16 brow[MS_T];
  int isbf = *flag;
  int tid = threadIdx.x;
  int tbase = blockIdx.x * MS_T;

  for (int b = tid; b <= NB; b += 256) hist[b] = 0;
  for (int b = tid; b < NB; b += 256)
    gbase[b] = boffs[b] + base[(size_t)blockIdx.x * NB + b];
  __syncthreads();

  int bk[MS_PT], ofs[MS_PT], cl[MS_PT], vb[MS_PT];
#pragma unroll
  for (int i = 0; i < MS_PT; ++i) {
    int e = tbase + i * 256 + tid;
    if (e < E) {
      int r = rows[e];
      bk[i] = r >> RBSH;
      cl[i] = cols[e] | ((r & (RB - 1)) << 17);
      float v;
      if (isbf) v = b2f(((const u16*)valsv)[e]);
      else      v = ((const float*)valsv)[e];
      vb[i] = __float_as_int(v);
      ofs[i] = atomicAdd(&hist[bk[i]], 1);
    } else {
      bk[i] = -1; ofs[i] = 0; cl[i] = 0; vb[i] = 0;
    }
  }
  __syncthreads();

  // exclusive prefix of hist[0..NB) in place; hist[NB] = total
  int K = (NB + 255) >> 8;
  int lo = tid * K, hi = lo + K;
  if (hi > NB) hi = NB;
  if (lo > NB) lo = NB;
  int s = 0;
  for (int b = lo; b < hi; ++b) s += hist[b];
  part[tid] = s;
  __syncthreads();
  for (int o = 1; o < 256; o <<= 1) {
    int v = (tid >= o) ? part[tid - o] : 0;
    __syncthreads();
    part[tid] += v;
    __syncthreads();
  }
  int run = part[tid] - s;
  for (int b = lo; b < hi; ++b) {
    int c = hist[b];
    hist[b] = run;
    run += c;
  }
  if (tid == 255) hist[NB] = part[255];
  __syncthreads();

  // scatter to LDS (sorted by bucket)
#pragma unroll
  for (int i = 0; i < MS_PT; ++i) {
    if (bk[i] >= 0) {
      int slot = hist[bk[i]] + ofs[i];
      buf[slot] = make_int2(cl[i], vb[i]);
      brow[slot] = (u16)bk[i];
    }
  }
  __syncthreads();

  // coalesced-run copy out via precomputed bases
  int tot = hist[NB];
  for (int i = tid; i < tot; i += 256) {
    int b = brow[i];
    pack[gbase[b] + (i - hist[b])] = buf[i];
  }
}

// ---------------- pass D: per-bucket 256-bin counting sort -> exact CSR ----------------
__global__ __launch_bounds__(256) void ms2_k(const int* __restrict__ boffs,
                                             const int2* __restrict__ pack,
                                             int2* __restrict__ pack2,
                                             int* __restrict__ offs, int N, int NB) {
  __shared__ int bins[RB];
  __shared__ int part[256];
  int b = blockIdx.x;
  int tid = threadIdx.x;
  int beg = boffs[b], end = boffs[b + 1];
  bins[tid] = 0;
  __syncthreads();
  for (int i = beg + tid; i < end; i += 256)
    atomicAdd(&bins[(pack[i].x >> 17) & (RB - 1)], 1);
  __syncthreads();
  int c = bins[tid];
  part[tid] = c;
  __syncthreads();
  for (int o = 1; o < 256; o <<= 1) {
    int v = (tid >= o) ? part[tid - o] : 0;
    __syncthreads();
    part[tid] += v;
    __syncthreads();
  }
  int pfx = part[tid] - c;  // exclusive
  __syncthreads();
  int n = b * RB + tid;
  if (n < N) offs[n] = beg + pfx;
  if (b == NB - 1 && tid == 0) offs[N] = end;
  bins[tid] = pfx;  // cursors
  __syncthreads();
  for (int i = beg + tid; i < end; i += 256) {
    int2 q = pack[i];
    int r = (q.x >> 17) & (RB - 1);
    int p = atomicAdd(&bins[r], 1);
    pack2[beg + p] = q;
  }
}

// ---------------- W -> bf16, transposed: Wt[n][k] = W[k][n] ----------------
__global__ void wtr_k(const int* __restrict__ flag, const void* __restrict__ Wv,
                      u16* __restrict__ Wt) {
  int isbf = *flag;
  int i = blockIdx.x * 256 + threadIdx.x;  // 65536 total
  int n = i >> 8, k = i & 255;
  float w;
  if (isbf) w = b2f(((const u16*)Wv)[k * 256 + n]);
  else      w = ((const float*)Wv)[k * 256 + n];
  Wt[n * 256 + k] = f2b(w);
}

// ---------------- P = emb @ W via MFMA bf16 (fragment layout m89-verified) ----------------
__global__ __launch_bounds__(256) void proj_k(const int* __restrict__ flag,
                                              const void* __restrict__ embv,
                                              const u16* __restrict__ Wt,
                                              u16* __restrict__ P, int N) {
  int isbf = *flag;
  int wave = threadIdx.x >> 6, lane = threadIdx.x & 63;
  int lr = lane & 15, lq = lane >> 4;
  int m0 = blockIdx.x * 64;
  int n0 = wave * 64;

  f32x4 acc[4][4];
#pragma unroll
  for (int mi = 0; mi < 4; ++mi)
#pragma unroll
    for (int ni = 0; ni < 4; ++ni) acc[mi][ni] = (f32x4)0.f;

  int arow[4];
#pragma unroll
  for (int mi = 0; mi < 4; ++mi) {
    int r = m0 + mi * 16 + lr;
    arow[mi] = r < N ? r : N - 1;
  }

  for (int ks = 0; ks < 8; ++ks) {
    int kb = ks * 32 + lq * 8;
    short8v a[4], b[4];
#pragma unroll
    for (int mi = 0; mi < 4; ++mi) {
      if (isbf) {
        a[mi] = *(const short8v*)((const u16*)embv + (size_t)arow[mi] * 256 + kb);
      } else {
        const float* p = (const float*)embv + (size_t)arow[mi] * 256 + kb;
        float4 x = *(const float4*)p;
        float4 y = *(const float4*)(p + 4);
        short8v t;
        t[0] = (short)f2b(x.x); t[1] = (short)f2b(x.y);
        t[2] = (short)f2b(x.z); t[3] = (short)f2b(x.w);
        t[4] = (short)f2b(y.x); t[5] = (short)f2b(y.y);
        t[6] = (short)f2b(y.z); t[7] = (short)f2b(y.w);
        a[mi] = t;
      }
    }
#pragma unroll
    for (int ni = 0; ni < 4; ++ni)
      b[ni] = *(const short8v*)(Wt + (size_t)(n0 + ni * 16 + lr) * 256 + kb);
#pragma unroll
    for (int mi = 0; mi < 4; ++mi)
#pragma unroll
      for (int ni = 0; ni < 4; ++ni)
        acc[mi][ni] = __builtin_amdgcn_mfma_f32_16x16x32_bf16(a[mi], b[ni], acc[mi][ni], 0, 0, 0);
  }

#pragma unroll
  for (int mi = 0; mi < 4; ++mi) {
    int rbase = m0 + mi * 16 + lq * 4;
#pragma unroll
    for (int ni = 0; ni < 4; ++ni) {
      int col = n0 + ni * 16 + lr;
#pragma unroll
      for (int r = 0; r < 4; ++r) {
        int row = rbase + r;
        if (row < N) P[(size_t)row * 256 + col] = f2b(acc[mi][ni][r]);
      }
    }
  }
}

// ---------------- aggregation: wave/node, pair-gather ----------------
// out[n][d] = relu( sum_e val_e * P[col_e][d] ).  Lanes 0-31 fetch edge j's
// P row (16B/lane), lanes 32-63 edge j+1's: 1KB per load instruction, 8
// pairs (16 edges) in flight. Halves combined once per node via shfl.
__global__ __launch_bounds__(256) void agg_k(const int* __restrict__ flag,
                                             const u16* __restrict__ P,
                                             const int* __restrict__ offs,
                                             const int2* __restrict__ pack,
                                             void* __restrict__ outv, int N) {
  int outbf = *flag;
  int wave = threadIdx.x >> 6, lane = threadIdx.x & 63;
  int node = blockIdx.x * 4 + wave;
  if (node >= N) return;
  int sub = lane & 31, half = lane >> 5;
  int beg = offs[node], end = offs[node + 1];
  const u16* pb = P + sub * 8;

  float acc[8];
#pragma unroll
  for (int k = 0; k < 8; ++k) acc[k] = 0.f;

  for (int j = beg; j < end; j += 16) {
#pragma unroll
    for (int k = 0; k < 8; ++k) {
      int i0 = j + 2 * k + half;           // my edge (uniform per half)
      int ic = i0 < end ? i0 : end - 1;    // clamped load index
      int2 q = pack[ic];
      float v = i0 < end ? __int_as_float(q.y) : 0.f;
      const int4* src = (const int4*)(pb + (size_t)(q.x & 0x1FFFF) * 256);
      int4 u = *src;
      acc[0] += v * blo((unsigned)u.x); acc[1] += v * bhi((unsigned)u.x);
      acc[2] += v * blo((unsigned)u.y); acc[3] += v * bhi((unsigned)u.y);
      acc[4] += v * blo((unsigned)u.z); acc[5] += v * bhi((unsigned)u.z);
      acc[6] += v * blo((unsigned)u.w); acc[7] += v * bhi((unsigned)u.w);
    }
  }

  // combine halves: lane l += lane l^32 (same dims, other edge parity)
#pragma unroll
  for (int k = 0; k < 8; ++k) acc[k] += __shfl(acc[k], lane ^ 32);

#pragma unroll
  for (int k = 0; k < 8; ++k) acc[k] = fmaxf(acc[k], 0.f);
  int d0 = sub * 8 + half * 4;
  if (outbf) {
    ushort4 o;
    o.x = f2b(acc[half * 4 + 0]); o.y = f2b(acc[half * 4 + 1]);
    o.z = f2b(acc[half * 4 + 2]); o.w = f2b(acc[half * 4 + 3]);
    *(ushort4*)((u16*)outv + (size_t)node * 256 + d0) = o;
  } else {
    float4 o;
    o.x = acc[half * 4 + 0]; o.y = acc[half * 4 + 1];
    o.z = acc[half * 4 + 2]; o.w = acc[half * 4 + 3];
    *(float4*)((float*)outv + (size_t)node * 256 + d0) = o;
  }
}

// ---------------- launch ----------------

extern "C" void kernel_launch(void* const* d_in, const int* in_sizes, int n_in,
                              void* d_out, int out_size, void* d_ws, size_t ws_size,
                              hipStream_t stream) {
  const void* emb  = d_in[0];
  const int*  rows = (const int*)d_in[1];
  const int*  cols = (const int*)d_in[2];
  const void* vals = d_in[3];
  const void* W    = d_in[4];

  int N = in_sizes[0] / 256;
  int E = in_sizes[1];
  int NB = (N + RB - 1) >> RBSH;
  int NBLK = (E + MS_T - 1) / MS_T;

  char* ws = (char*)d_ws;
  size_t off = 0;
  auto carve = [&](size_t bytes) -> char* {
    char* p = ws + off;
    off += (bytes + 511) & ~(size_t)511;
    return p;
  };
  int*  flag   = (int*) carve(4);
  int*  cnt    = (int*) carve((size_t)NBLK * NB * 4);  // counts -> prefixes
  int*  totals = (int*) carve((size_t)NB * 4);
  int*  boffs  = (int*) carve((size_t)(NB + 1) * 4);
  int*  offs   = (int*) carve((size_t)(N + 1) * 4);
  int2* pack   = (int2*)carve((size_t)E * 8);
  int2* pack2  = (int2*)carve((size_t)E * 8);
  u16*  P      = (u16*) carve((size_t)N * 256 * 2);
  u16*  Wt     = (u16*) carve((size_t)256 * 256 * 2);
  (void)ws_size; (void)n_in; (void)out_size;

  detect_k<<<1, 256, 0, stream>>>((const unsigned*)vals, flag);

  count_k<<<NBLK, 256, 0, stream>>>(rows, cnt, E, NB);
  rowscan_k<<<NB, 256, 0, stream>>>(cnt, totals, NB, NBLK);
  boffscan_k<<<1, 512, 0, stream>>>(totals, boffs, NB);

  wtr_k<<<256, 256, 0, stream>>>(flag, W, Wt);

  int pb = (N + 63) / 64;
  proj_k<<<pb, 256, 0, stream>>>(flag, emb, Wt, P, N);

  place_k<<<NBLK, 256, 0, stream>>>(flag, rows, cols, vals, cnt, boffs, pack, E, NB);

  ms2_k<<<NB, 256, 0, stream>>>(boffs, pack, pack2, offs, N, NB);

  int ab = (N + 3) / 4;
  agg_k<<<ab, 256, 0, stream>>>(flag, P, offs, pack2, d_out, N);
}

// Round 6
// 566.868 us; speedup vs baseline: 1.4641x; 1.0342x over previous
//
#include <hip/hip_runtime.h>
#include <stdint.h>

// GCN layer: out = relu( segment_sum(vals * emb[cols], rows) @ W )
// Reordered: out = relu( segment_sum(vals * P[cols], rows) ), P = emb @ W.
// Deterministic, global-atomic-free pipeline (8 launches):
//   count_k (per-block,bucket counts + dtype detect) -> rowscan_k ->
//   boffscan_k -> wtr (W^T bf16) -> proj (P=emb@W MFMA) -> place_k
//   (LDS multisplit, copy-out via precomputed bases) -> ms2_k (per-bucket
//   256-bin counting sort -> exact CSR) -> agg_k (wave/node gather).
// Round-5 lesson: compiler re-interleaves phased gather loads to save VGPRs
// (VGPR=36 => ~2 gathers in flight, latency-bound). sched_barrier(0) fences
// pin the load/FMA phases apart. place_k LDS 45->25KB (3->6 blocks/CU),
// ms2_k 512 threads, detect folded into count_k.

typedef unsigned short u16;
typedef __attribute__((ext_vector_type(8))) short short8v;  // 8 bf16
typedef __attribute__((ext_vector_type(4))) float f32x4;    // MFMA C/D

#define RBSH 8
#define RB 256           // rows per bucket
#define NBMAX 512        // supports N <= 131072
#define MS_T 2048        // edges per multisplit tile
#define MS_PT 8          // edges per thread (256 threads)

__device__ __forceinline__ float b2f(u16 u) {
  union { unsigned i; float f; } x; x.i = ((unsigned)u) << 16; return x.f;
}
__device__ __forceinline__ u16 f2b(float f) {
  union { unsigned i; float f; } x; x.f = f;
  unsigned r = x.i + 0x7fffu + ((x.i >> 16) & 1u);
  return (u16)(r >> 16);
}
__device__ __forceinline__ float blo(unsigned u) {
  union { unsigned i; float f; } x; x.i = u << 16; return x.f;
}
__device__ __forceinline__ float bhi(unsigned u) {
  union { unsigned i; float f; } x; x.i = u & 0xFFFF0000u; return x.f;
}

// ---------------- pass A: per-(block,bucket) counts + dtype detect ----------------
// dtype detect: adj_vals ~ U[0,1). As f32 words, low16 uniform (>=0x3F80
// ~75%). As packed bf16 pairs, low16 is bf16 in [0,1) -> <0x3F80.
__global__ __launch_bounds__(256) void count_k(const int* __restrict__ rows,
                                               const unsigned* __restrict__ valsw,
                                               int* __restrict__ flag,
                                               int* __restrict__ cnt, int E, int NB) {
  __shared__ int h[NBMAX];
  __shared__ int dcnt;
  int tid = threadIdx.x;
  for (int b = tid; b < NB; b += 256) h[b] = 0;
  if (blockIdx.x == 0 && tid == 0) dcnt = 0;
  __syncthreads();
  if (blockIdx.x == 0) {
    int dlim = E < 4096 ? E : 4096;
    int c = 0;
    for (int i = tid; i < dlim; i += 256) {
      unsigned w = valsw[i];
      if ((w & 0xFFFFu) >= 0x3F80u) c++;
    }
    atomicAdd(&dcnt, c);
  }
  int base = blockIdx.x * MS_T;
#pragma unroll
  for (int i = 0; i < MS_PT; ++i) {
    int e = base + i * 256 + tid;
    if (e < E) atomicAdd(&h[rows[e] >> RBSH], 1);
  }
  __syncthreads();
  for (int b = tid; b < NB; b += 256) cnt[(size_t)blockIdx.x * NB + b] = h[b];
  if (blockIdx.x == 0 && tid == 0) {
    int dlim = E < 4096 ? E : 4096;
    *flag = (dcnt < (dlim >> 2)) ? 1 : 0;
  }
}

// ---------------- pass B1: within-bucket prefix over count-blocks ----------------
// One block per bucket. cnt[blk*NB + b] -> exclusive prefix (in place);
// totals[b] = bucket total.
__global__ __launch_bounds__(256) void rowscan_k(int* __restrict__ cnt,
                                                 int* __restrict__ totals,
                                                 int NB, int NBLK) {
  __shared__ int part[256];
  int b = blockIdx.x, tid = threadIdx.x;
  int K = (NBLK + 255) >> 8;  // <= 8 for NBLK <= 2048
  int lo = tid * K;
  int v[8];
  int s = 0;
#pragma unroll
  for (int u = 0; u < 8; ++u) {
    int i = lo + u;
    v[u] = (u < K && i < NBLK) ? cnt[(size_t)i * NB + b] : 0;
    s += v[u];
  }
  part[tid] = s;
  __syncthreads();
  for (int o = 1; o < 256; o <<= 1) {
    int t = (tid >= o) ? part[tid - o] : 0;
    __syncthreads();
    part[tid] += t;
    __syncthreads();
  }
  int run = part[tid] - s;  // exclusive base for this thread's range
#pragma unroll
  for (int u = 0; u < 8; ++u) {
    int i = lo + u;
    if (u < K && i < NBLK) cnt[(size_t)i * NB + b] = run;
    run += v[u];
  }
  if (tid == 255) totals[b] = part[255];
}

// ---------------- pass B2: bucket bases (1 block, NB <= 512) ----------------
__global__ __launch_bounds__(512) void boffscan_k(const int* __restrict__ totals,
                                                  int* __restrict__ boffs, int NB) {
  __shared__ int part[512];
  int tid = threadIdx.x;
  int c = (tid < NB) ? totals[tid] : 0;
  part[tid] = c;
  __syncthreads();
  for (int o = 1; o < 512; o <<= 1) {
    int t = (tid >= o) ? part[tid - o] : 0;
    __syncthreads();
    part[tid] += t;
    __syncthreads();
  }
  if (tid < NB) boffs[tid] = part[tid] - c;
  if (tid == 511) boffs[NB] = part[511];
}

// ---------------- pass C: LDS multisplit place (no global atomics) ----------------
// Entry: x = col | ((row & 255) << 17)  (col < 2^17), y = f32 bits of val.
__global__ __launch_bounds__(256) void place_k(const int* __restrict__ flag,
                                               const int* __restrict__ rows,
                                               const int* __restrict__ cols,
                                               const void* __restrict__ valsv,
                                               const int* __restrict__ base,
                                               const int* __restrict__ boffs,
                                               int2* __restrict__ pack, int E, int NB) {
  __shared__ int hist[NBMAX + 1];  // becomes exclusive prefix
  __shared__ int gbase[NBMAX];
  __shared__ int part[256];
  __shared__ int2 buf[MS_T];
  __shared__ u16 brow[MS_T];
  int isbf = *flag;
  int tid = threadIdx.x;
  int tbase = blockIdx.x * MS_T;

  for (int b = tid; b <= NB; b += 256) hist[b] = 0;
  for (int b = tid; b < NB; b += 256)
    gbase[b] = boffs[b] + base[(size_t)blockIdx.x * NB + b];
  __syncthreads();

  int bk[MS_PT], ofs[MS_PT], cl[MS_PT], vb[MS_PT];
#pragma unroll
  for (int i = 0; i < MS_PT; ++i) {
    int e = tbase + i * 256 + tid;
    if (e < E) {
      int r = rows[e];
      bk[i] = r >> RBSH;
      cl[i] = cols[e] | ((r & (RB - 1)) << 17);
      float v;
      if (isbf) v = b2f(((const u16*)valsv)[e]);
      else      v = ((const float*)valsv)[e];
      vb[i] = __float_as_int(v);
      ofs[i] = atomicAdd(&hist[bk[i]], 1);
    } else {
      bk[i] = -1; ofs[i] = 0; cl[i] = 0; vb[i] = 0;
    }
  }
  __syncthreads();

  // exclusive prefix of hist[0..NB) in place; hist[NB] = total
  int K = (NB + 255) >> 8;
  int lo = tid * K, hi = lo + K;
  if (hi > NB) hi = NB;
  if (lo > NB) lo = NB;
  int s = 0;
  for (int b = lo; b < hi; ++b) s += hist[b];
  part[tid] = s;
  __syncthreads();
  for (int o = 1; o < 256; o <<= 1) {
    int v = (tid >= o) ? part[tid - o] : 0;
    __syncthreads();
    part[tid] += v;
    __syncthreads();
  }
  int run = part[tid] - s;
  for (int b = lo; b < hi; ++b) {
    int c = hist[b];
    hist[b] = run;
    run += c;
  }
  if (tid == 255) hist[NB] = part[255];
  __syncthreads();

  // scatter to LDS (sorted by bucket)
#pragma unroll
  for (int i = 0; i < MS_PT; ++i) {
    if (bk[i] >= 0) {
      int slot = hist[bk[i]] + ofs[i];
      buf[slot] = make_int2(cl[i], vb[i]);
      brow[slot] = (u16)bk[i];
    }
  }
  __syncthreads();

  // coalesced-run copy out via precomputed bases
  int tot = hist[NB];
  for (int i = tid; i < tot; i += 256) {
    int b = brow[i];
    pack[gbase[b] + (i - hist[b])] = buf[i];
  }
}

// ---------------- pass D: per-bucket 256-bin counting sort -> exact CSR ----------------
__global__ __launch_bounds__(512) void ms2_k(const int* __restrict__ boffs,
                                             const int2* __restrict__ pack,
                                             int2* __restrict__ pack2,
                                             int* __restrict__ offs, int N, int NB) {
  __shared__ int bins[RB];
  __shared__ int part[256];
  int b = blockIdx.x;
  int tid = threadIdx.x;
  int beg = boffs[b], end = boffs[b + 1];
  if (tid < RB) bins[tid] = 0;
  __syncthreads();
  for (int i = beg + tid; i < end; i += 512)
    atomicAdd(&bins[(pack[i].x >> 17) & (RB - 1)], 1);
  __syncthreads();
  int c = (tid < 256) ? bins[tid] : 0;
  if (tid < 256) part[tid] = c;
  __syncthreads();
  for (int o = 1; o < 256; o <<= 1) {
    int v = (tid < 256 && tid >= o) ? part[tid - o] : 0;
    __syncthreads();
    if (tid < 256) part[tid] += v;
    __syncthreads();
  }
  if (tid < 256) {
    int pfx = part[tid] - c;  // exclusive
    int n = b * RB + tid;
    if (n < N) offs[n] = beg + pfx;
    bins[tid] = pfx;  // cursors
  }
  if (b == NB - 1 && tid == 0) offs[N] = end;
  __syncthreads();
  for (int i = beg + tid; i < end; i += 512) {
    int2 q = pack[i];
    int r = (q.x >> 17) & (RB - 1);
    int p = atomicAdd(&bins[r], 1);
    pack2[beg + p] = q;
  }
}

// ---------------- W -> bf16, transposed: Wt[n][k] = W[k][n] ----------------
__global__ void wtr_k(const int* __restrict__ flag, const void* __restrict__ Wv,
                      u16* __restrict__ Wt) {
  int isbf = *flag;
  int i = blockIdx.x * 256 + threadIdx.x;  // 65536 total
  int n = i >> 8, k = i & 255;
  float w;
  if (isbf) w = b2f(((const u16*)Wv)[k * 256 + n]);
  else      w = ((const float*)Wv)[k * 256 + n];
  Wt[n * 256 + k] = f2b(w);
}

// ---------------- P = emb @ W via MFMA bf16 (fragment layout m89-verified) ----------------
__global__ __launch_bounds__(256) void proj_k(const int* __restrict__ flag,
                                              const void* __restrict__ embv,
                                              const u16* __restrict__ Wt,
                                              u16* __restrict__ P, int N) {
  int isbf = *flag;
  int wave = threadIdx.x >> 6, lane = threadIdx.x & 63;
  int lr = lane & 15, lq = lane >> 4;
  int m0 = blockIdx.x * 64;
  int n0 = wave * 64;

  f32x4 acc[4][4];
#pragma unroll
  for (int mi = 0; mi < 4; ++mi)
#pragma unroll
    for (int ni = 0; ni < 4; ++ni) acc[mi][ni] = (f32x4)0.f;

  int arow[4];
#pragma unroll
  for (int mi = 0; mi < 4; ++mi) {
    int r = m0 + mi * 16 + lr;
    arow[mi] = r < N ? r : N - 1;
  }

  for (int ks = 0; ks < 8; ++ks) {
    int kb = ks * 32 + lq * 8;
    short8v a[4], b[4];
#pragma unroll
    for (int mi = 0; mi < 4; ++mi) {
      if (isbf) {
        a[mi] = *(const short8v*)((const u16*)embv + (size_t)arow[mi] * 256 + kb);
      } else {
        const float* p = (const float*)embv + (size_t)arow[mi] * 256 + kb;
        float4 x = *(const float4*)p;
        float4 y = *(const float4*)(p + 4);
        short8v t;
        t[0] = (short)f2b(x.x); t[1] = (short)f2b(x.y);
        t[2] = (short)f2b(x.z); t[3] = (short)f2b(x.w);
        t[4] = (short)f2b(y.x); t[5] = (short)f2b(y.y);
        t[6] = (short)f2b(y.z); t[7] = (short)f2b(y.w);
        a[mi] = t;
      }
    }
#pragma unroll
    for (int ni = 0; ni < 4; ++ni)
      b[ni] = *(const short8v*)(Wt + (size_t)(n0 + ni * 16 + lr) * 256 + kb);
#pragma unroll
    for (int mi = 0; mi < 4; ++mi)
#pragma unroll
      for (int ni = 0; ni < 4; ++ni)
        acc[mi][ni] = __builtin_amdgcn_mfma_f32_16x16x32_bf16(a[mi], b[ni], acc[mi][ni], 0, 0, 0);
  }

#pragma unroll
  for (int mi = 0; mi < 4; ++mi) {
    int rbase = m0 + mi * 16 + lq * 4;
#pragma unroll
    for (int ni = 0; ni < 4; ++ni) {
      int col = n0 + ni * 16 + lr;
#pragma unroll
      for (int r = 0; r < 4; ++r) {
        int row = rbase + r;
        if (row < N) P[(size_t)row * 256 + col] = f2b(acc[mi][ni][r]);
      }
    }
  }
}

// ---------------- aggregation: wave/node, phased pair-gather ----------------
// out[n][d] = relu( sum_e val_e * P[col_e][d] ). 16-edge flat batches:
// phase1 = 8 pack loads, phase2 = 8 paired 512B P gathers (lanes 0-31 edge
// 2k, lanes 32-63 edge 2k+1), phase3 = FMAs. sched_barrier(0) fences keep
// the phases apart so all 8 gathers stay in flight (round-5: compiler
// re-interleaved to VGPR=36 => ~2 in flight, latency-bound).
__global__ __launch_bounds__(256) void agg_k(const int* __restrict__ flag,
                                             const u16* __restrict__ P,
                                             const int* __restrict__ offs,
                                             const int2* __restrict__ pack,
                                             void* __restrict__ outv, int N) {
  int outbf = *flag;
  int wave = threadIdx.x >> 6, lane = threadIdx.x & 63;
  int node = blockIdx.x * 4 + wave;
  if (node >= N) return;
  int sub = lane & 31, half = lane >> 5;
  int beg = offs[node], end = offs[node + 1];
  const u16* pb = P + sub * 8;

  float acc[8];
#pragma unroll
  for (int k = 0; k < 8; ++k) acc[k] = 0.f;

  for (int j = beg; j < end; j += 16) {
#define LDQ(k) int i##k = j + 2 * k + half; \
               int2 q##k = pack[i##k < end ? i##k : end - 1];
    LDQ(0) LDQ(1) LDQ(2) LDQ(3) LDQ(4) LDQ(5) LDQ(6) LDQ(7)
#undef LDQ
    __builtin_amdgcn_sched_barrier(0);
#define LDU(k) int4 u##k = *(const int4*)(pb + (size_t)(q##k.x & 0x1FFFF) * 256); \
               float v##k = i##k < end ? __int_as_float(q##k.y) : 0.f;
    LDU(0) LDU(1) LDU(2) LDU(3) LDU(4) LDU(5) LDU(6) LDU(7)
#undef LDU
    __builtin_amdgcn_sched_barrier(0);
#define FMA8(k) { unsigned ux = (unsigned)u##k.x, uy = (unsigned)u##k.y; \
                  unsigned uz = (unsigned)u##k.z, uw = (unsigned)u##k.w; \
                  acc[0] += v##k * blo(ux); acc[1] += v##k * bhi(ux); \
                  acc[2] += v##k * blo(uy); acc[3] += v##k * bhi(uy); \
                  acc[4] += v##k * blo(uz); acc[5] += v##k * bhi(uz); \
                  acc[6] += v##k * blo(uw); acc[7] += v##k * bhi(uw); }
    FMA8(0) FMA8(1) FMA8(2) FMA8(3) FMA8(4) FMA8(5) FMA8(6) FMA8(7)
#undef FMA8
  }

  // combine halves: lane l += lane l^32 (same dims, other edge parity)
#pragma unroll
  for (int k = 0; k < 8; ++k) acc[k] += __shfl(acc[k], lane ^ 32);

#pragma unroll
  for (int k = 0; k < 8; ++k) acc[k] = fmaxf(acc[k], 0.f);
  int d0 = sub * 8 + half * 4;
  if (outbf) {
    ushort4 o;
    o.x = f2b(acc[half * 4 + 0]); o.y = f2b(acc[half * 4 + 1]);
    o.z = f2b(acc[half * 4 + 2]); o.w = f2b(acc[half * 4 + 3]);
    *(ushort4*)((u16*)outv + (size_t)node * 256 + d0) = o;
  } else {
    float4 o;
    o.x = acc[half * 4 + 0]; o.y = acc[half * 4 + 1];
    o.z = acc[half * 4 + 2]; o.w = acc[half * 4 + 3];
    *(float4*)((float*)outv + (size_t)node * 256 + d0) = o;
  }
}

// ---------------- launch ----------------

extern "C" void kernel_launch(void* const* d_in, const int* in_sizes, int n_in,
                              void* d_out, int out_size, void* d_ws, size_t ws_size,
                              hipStream_t stream) {
  const void* emb  = d_in[0];
  const int*  rows = (const int*)d_in[1];
  const int*  cols = (const int*)d_in[2];
  const void* vals = d_in[3];
  const void* W    = d_in[4];

  int N = in_sizes[0] / 256;
  int E = in_sizes[1];
  int NB = (N + RB - 1) >> RBSH;
  int NBLK = (E + MS_T - 1) / MS_T;

  char* ws = (char*)d_ws;
  size_t off = 0;
  auto carve = [&](size_t bytes) -> char* {
    char* p = ws + off;
    off += (bytes + 511) & ~(size_t)511;
    return p;
  };
  int*  flag   = (int*) carve(4);
  int*  cnt    = (int*) carve((size_t)NBLK * NB * 4);  // counts -> prefixes
  int*  totals = (int*) carve((size_t)NB * 4);
  int*  boffs  = (int*) carve((size_t)(NB + 1) * 4);
  int*  offs   = (int*) carve((size_t)(N + 1) * 4);
  int2* pack   = (int2*)carve((size_t)E * 8);
  int2* pack2  = (int2*)carve((size_t)E * 8);
  u16*  P      = (u16*) carve((size_t)N * 256 * 2);
  u16*  Wt     = (u16*) carve((size_t)256 * 256 * 2);
  (void)ws_size; (void)n_in; (void)out_size;

  count_k<<<NBLK, 256, 0, stream>>>(rows, (const unsigned*)vals, flag, cnt, E, NB);
  rowscan_k<<<NB, 256, 0, stream>>>(cnt, totals, NB, NBLK);
  boffscan_k<<<1, 512, 0, stream>>>(totals, boffs, NB);

  wtr_k<<<256, 256, 0, stream>>>(flag, W, Wt);

  int pb = (N + 63) / 64;
  proj_k<<<pb, 256, 0, stream>>>(flag, emb, Wt, P, N);

  place_k<<<NBLK, 256, 0, stream>>>(flag, rows, cols, vals, cnt, boffs, pack, E, NB);

  ms2_k<<<NB, 512, 0, stream>>>(boffs, pack, pack2, offs, N, NB);

  int ab = (N + 3) / 4;
  agg_k<<<ab, 256, 0, stream>>>(flag, P, offs, pack2, d_out, N);
}